// Round 2
// baseline (1060.502 us; speedup 1.0000x reference)
//
#include <hip/hip_runtime.h>
#include <stdint.h>
#include <stddef.h>

// Problem constants
#define BSZ 128
#define CIN 32
#define COUT 32
#define HN 4096
#define K7 7
#define NTOT (BSZ*CIN*HN)     // 16,777,216 x elements
#define NBH  (BSZ*HN)         // 524,288 (b,h) pairs

typedef __attribute__((ext_vector_type(8))) short short8;
typedef __attribute__((ext_vector_type(4))) float f32x4;

// ws layout (bytes)
#define WS_XT   0            // bf16 xt[B][H][32]            : 33,554,432 B
#define WS_WT   33554432     // bf16 wt[o][kk][c]            : 14,336 B
#define WS_NBR  33568768     // int32 nbr_pack[H][8]         : 131,072 B
#define WS_INVD 33699840     // float invd[H]                : 16,384 B
#define WS_STAT 33716224     // double sum,sumsq ; float osum[32], osumsq[32]

__device__ __forceinline__ unsigned short f32_to_bf16(float f){
    union { float f; uint32_t u; } v; v.f = f;
    uint32_t u = v.u;
    return (unsigned short)((u + 0x7FFFu + ((u >> 16) & 1u)) >> 16);
}

// ---------------------------------------------------------------------------
// kprep: zero stats, build packed neighbor table + 1/denominator per hex
// NOTE: harness passes integer inputs as int32 (NOT the reference's int64).
__global__ void kprep(const int* __restrict__ nbr,
                      int* __restrict__ nbr_pack,
                      float* __restrict__ invd,
                      double* __restrict__ dsum,
                      float* __restrict__ ostat){
    int t = blockIdx.x*blockDim.x + threadIdx.x;
    if (blockIdx.x == 0){
        if (threadIdx.x < 2)  dsum[threadIdx.x] = 0.0;
        if (threadIdx.x < 64) ostat[threadIdx.x] = 0.0f;
    }
    if (t < HN){
        int cnt = 0;
        int pk[8];
        pk[0] = t;                       // self tap (k=0)
        #pragma unroll
        for (int j = 0; j < 6; j++){
            int iv = nbr[t*6 + j];
            if (iv >= HN) iv = HN - 1;   // safety clamp (never expected)
            if (iv >= 0) cnt++; else iv = -1;
            pk[1+j] = iv;
        }
        pk[7] = 0;
        #pragma unroll
        for (int j = 0; j < 8; j++) nbr_pack[t*8 + j] = pk[j];
        invd[t] = 1.0f / ((float)cnt + 1.0f + 1e-6f);
    }
}

// ---------------------------------------------------------------------------
// ktrans: x[B][C][H] f32 -> xt[B][H][C] bf16, fused global sum/sumsq reduce.
// grid = 128 b * 64 h-tiles = 8192 blocks of 256
__global__ void ktrans(const float* __restrict__ x,
                       unsigned short* __restrict__ xt,
                       double* __restrict__ dsum){
    __shared__ float tile[32][65];
    __shared__ double red[8];
    int b  = blockIdx.x >> 6;
    int h0 = (blockIdx.x & 63) << 6;
    int t  = threadIdx.x;
    int hh = t & 63;
    int cq = t >> 6;                      // 0..3
    double ds = 0.0, ds2 = 0.0;
    #pragma unroll
    for (int rep = 0; rep < 8; rep++){
        int c = rep*4 + cq;
        float v = x[((size_t)(b*32 + c))*HN + h0 + hh];
        tile[c][hh] = v;
        double dv = (double)v;
        ds += dv; ds2 += dv*dv;
    }
    // wave + block reduce for std
    #pragma unroll
    for (int off = 32; off; off >>= 1){
        ds  += __shfl_down(ds,  off);
        ds2 += __shfl_down(ds2, off);
    }
    int lane = t & 63, wv = t >> 6;
    if (lane == 0){ red[wv] = ds; red[4+wv] = ds2; }
    __syncthreads();
    if (t == 0){
        atomicAdd(&dsum[0], red[0]+red[1]+red[2]+red[3]);
        atomicAdd(&dsum[1], red[4]+red[5]+red[6]+red[7]);
    }
    // transposed bf16 write: 16B per thread, fully coalesced per wave
    int hw = t >> 2;
    int cg = (t & 3) * 8;
    alignas(16) unsigned short tmp[8];
    #pragma unroll
    for (int j = 0; j < 8; j++) tmp[j] = f32_to_bf16(tile[cg + j][hw]);
    *(uint4*)(xt + ((size_t)(b*HN + h0 + hw))*32 + cg) = *(const uint4*)tmp;
}

// ---------------------------------------------------------------------------
// kwt: fold 1/(std+1e-5) into weights; pack to wt[o][kk][c] bf16 (A-frag order)
__global__ void kwt(const float* __restrict__ w,
                    const double* __restrict__ dsum,
                    unsigned short* __restrict__ wt){
    double sum = dsum[0], sumsq = dsum[1];
    double mean = sum / (double)NTOT;
    double var  = (sumsq - (double)NTOT*mean*mean) / (double)(NTOT - 1);
    float inv_s = 1.0f / ((float)sqrt(var) + 1e-5f);
    for (int i = threadIdx.x; i < COUT*K7*CIN; i += blockDim.x){
        int o  = i / (K7*CIN);
        int kk = (i / CIN) % K7;
        int c  = i % CIN;
        float val = w[(o*CIN + c)*K7 + kk] * inv_s;
        wt[i] = f32_to_bf16(val);
    }
}

// ---------------------------------------------------------------------------
// kconv: gather + MFMA GEMM + /D + bias, write out_pre, accumulate BN stats.
// Per wave-tile: 16 pairs (consecutive h, one b). M=32 (2 m-tiles), K=224 (7 taps).
// grid = 1024 blocks * 256 threads = 4096 waves; 32768 tiles -> 8 per wave.
__global__ __launch_bounds__(256) void kconv(
    const unsigned short* __restrict__ xt,
    const unsigned short* __restrict__ wt,
    const int* __restrict__ nbrp,
    const float* __restrict__ invd,
    const float* __restrict__ bias,
    float* __restrict__ out,
    float* __restrict__ ostat)
{
    int lane = threadIdx.x & 63;
    int wv   = threadIdx.x >> 6;
    int wgid = blockIdx.x*4 + wv;         // 0..4095
    int n    = lane & 15;
    int quad = lane >> 4;

    // A fragments (W) in registers: lane holds W[o=n+16mt][ik=kk*32 + quad*8 + j]
    short8 af[2][K7];
    #pragma unroll
    for (int mt = 0; mt < 2; mt++){
        int o = n + 16*mt;
        #pragma unroll
        for (int kk = 0; kk < K7; kk++)
            af[mt][kk] = *(const short8*)(wt + (size_t)(o*K7 + kk)*CIN + quad*8);
    }
    // bias for this lane's 8 output channels (o = mt*16 + quad*4 + r)
    float bias8[2][4];
    #pragma unroll
    for (int mt = 0; mt < 2; mt++)
        #pragma unroll
        for (int r = 0; r < 4; r++)
            bias8[mt][r] = bias[mt*16 + quad*4 + r];

    float sacc[8]  = {0,0,0,0,0,0,0,0};
    float sacc2[8] = {0,0,0,0,0,0,0,0};
    const short8 zero8 = {0,0,0,0,0,0,0,0};

    for (int tilei = wgid; tilei < (NBH/16); tilei += 4096){
        int b  = tilei >> 8;              // 256 tiles per b
        int h0 = (tilei & 255) << 4;
        int h  = h0 + n;
        float idv = invd[h];
        const int* np = nbrp + h*8;

        // preload all 7 gathered B-fragments (independent loads, overlap latency)
        short8 bfr[K7];
        #pragma unroll
        for (int kk = 0; kk < K7; kk++){
            int row  = np[kk];
            int rowc = row < 0 ? 0 : row;
            bfr[kk] = *(const short8*)(xt + ((size_t)(b*HN + rowc))*32 + quad*8);
            if (row < 0) bfr[kk] = zero8;
        }
        f32x4 acc0 = {0.f,0.f,0.f,0.f};
        f32x4 acc1 = {0.f,0.f,0.f,0.f};
        #pragma unroll
        for (int kk = 0; kk < K7; kk++){
            acc0 = __builtin_amdgcn_mfma_f32_16x16x32_bf16(af[0][kk], bfr[kk], acc0, 0, 0, 0);
            acc1 = __builtin_amdgcn_mfma_f32_16x16x32_bf16(af[1][kk], bfr[kk], acc1, 0, 0, 0);
        }
        // epilogue: D[row=quad*4+r][col=n];  out[b][o][h], o = mt*16+quad*4+r
        #pragma unroll
        for (int mt = 0; mt < 2; mt++){
            f32x4 a = mt ? acc1 : acc0;
            #pragma unroll
            for (int r = 0; r < 4; r++){
                int o = mt*16 + quad*4 + r;
                float v = a[r]*idv + bias8[mt][r];
                out[((size_t)(b*COUT + o))*HN + h] = v;
                sacc[mt*4 + r]  += v;
                sacc2[mt*4 + r] += v*v;
            }
        }
    }
    // reduce BN partials over the 16 n-lanes
    #pragma unroll
    for (int bit = 1; bit < 16; bit <<= 1){
        #pragma unroll
        for (int i = 0; i < 8; i++){
            sacc[i]  += __shfl_xor(sacc[i],  bit);
            sacc2[i] += __shfl_xor(sacc2[i], bit);
        }
    }
    if (n == 0){
        #pragma unroll
        for (int mt = 0; mt < 2; mt++)
            #pragma unroll
            for (int r = 0; r < 4; r++){
                int o = mt*16 + quad*4 + r;
                atomicAdd(&ostat[o],      sacc[mt*4 + r]);
                atomicAdd(&ostat[32 + o], sacc2[mt*4 + r]);
            }
    }
}

// ---------------------------------------------------------------------------
// kbn: apply BatchNorm (training-mode, biased var) in place on d_out
__global__ void kbn(float4* __restrict__ out4,
                    const float* __restrict__ ostat,
                    const float* __restrict__ gamma,
                    const float* __restrict__ beta){
    __shared__ float sc[32], sh[32];
    int t = threadIdx.x;
    if (t < 32){
        float mean = ostat[t] * (1.0f/(float)NBH);
        float var  = ostat[32 + t] * (1.0f/(float)NBH) - mean*mean;
        float s = gamma[t] * rsqrtf(var + 1e-5f);
        sc[t] = s;
        sh[t] = beta[t] - mean*s;
    }
    __syncthreads();
    int gid    = blockIdx.x*blockDim.x + t;
    int stride = gridDim.x*blockDim.x;
    for (int i = gid; i < NTOT/4; i += stride){
        int o = (i >> 10) & 31;           // (i*4 / 4096) % 32
        float4 v = out4[i];
        float s = sc[o], b = sh[o];
        v.x = v.x*s + b; v.y = v.y*s + b; v.z = v.z*s + b; v.w = v.w*s + b;
        out4[i] = v;
    }
}

// ---------------------------------------------------------------------------
extern "C" void kernel_launch(void* const* d_in, const int* in_sizes, int n_in,
                              void* d_out, int out_size, void* d_ws, size_t ws_size,
                              hipStream_t stream) {
    const float* x      = (const float*)d_in[0];
    const float* weight = (const float*)d_in[1];
    const float* bias   = (const float*)d_in[2];
    const float* gamma  = (const float*)d_in[3];
    const float* beta   = (const float*)d_in[4];
    const int*   nbr    = (const int*)d_in[5];   // int64 in reference -> int32 from harness
    // d_in[6] = groups (==1), ignored

    char* ws = (char*)d_ws;
    unsigned short* xt   = (unsigned short*)(ws + WS_XT);
    unsigned short* wt   = (unsigned short*)(ws + WS_WT);
    int*            nbrp = (int*)(ws + WS_NBR);
    float*          invd = (float*)(ws + WS_INVD);
    double*         dsum = (double*)(ws + WS_STAT);
    float*          ostat= (float*)(ws + WS_STAT + 16);
    float*          out  = (float*)d_out;

    kprep <<<16,   256, 0, stream>>>(nbr, nbrp, invd, dsum, ostat);
    ktrans<<<8192, 256, 0, stream>>>(x, xt, dsum);
    kwt   <<<1,    256, 0, stream>>>(weight, dsum, wt);
    kconv <<<1024, 256, 0, stream>>>(xt, wt, nbrp, invd, bias, out, ostat);
    kbn   <<<2048, 256, 0, stream>>>((float4*)out, ostat, gamma, beta);
}

// Round 3
// 204.064 us; speedup vs baseline: 5.1969x; 5.1969x over previous
//
#include <hip/hip_runtime.h>
#include <stdint.h>
#include <stddef.h>

// Problem constants
#define BSZ 128
#define CIN 32
#define COUT 32
#define HN 4096
#define K7 7
#define NTOT (BSZ*CIN*HN)     // 16,777,216 x elements
#define NBH  (BSZ*HN)         // 524,288 (b,h) pairs

typedef __attribute__((ext_vector_type(8))) short short8;
typedef __attribute__((ext_vector_type(4))) float f32x4;

// ws layout (bytes)
#define WS_XT   0            // bf16 xt[B][H][32]            : 33,554,432 B
#define WS_WT   33554432     // bf16 wt[o][kk][c]            : 14,336 B
#define WS_NBR  33568768     // int32 nbr_pack[H][8]         : 131,072 B
#define WS_INVD 33699840     // float invd[H]                : 16,384 B
#define WS_DSP  33716224     // double dsp[256][2]           : 4,096 B   (std partials)
#define WS_OST  33720320     // float ostat[64]              : 256 B     (reduced BN stats)
#define WS_OSTP 33720576     // float ostatp[256][64]        : 65,536 B  (BN stat partials)

__device__ __forceinline__ unsigned short f32_to_bf16(float f){
    union { float f; uint32_t u; } v; v.f = f;
    uint32_t u = v.u;
    return (unsigned short)((u + 0x7FFFu + ((u >> 16) & 1u)) >> 16);
}

// ---------------------------------------------------------------------------
// kprep: zero stat partial buffers, build packed neighbor table + 1/denom.
// NOTE: harness passes integer inputs as int32 (NOT the reference's int64).
__global__ void kprep(const int* __restrict__ nbr,
                      int* __restrict__ nbr_pack,
                      float* __restrict__ invd,
                      double* __restrict__ dsp,
                      float* __restrict__ ostatp){
    int t = blockIdx.x*blockDim.x + threadIdx.x;   // 0..4095
    if (t < 512) dsp[t] = 0.0;
    #pragma unroll
    for (int j = 0; j < 4; j++) ostatp[t*4 + j] = 0.0f;   // 16384 floats
    if (t < HN){
        int cnt = 0;
        int pk[8];
        pk[0] = t;                       // self tap (k=0)
        #pragma unroll
        for (int j = 0; j < 6; j++){
            int iv = nbr[t*6 + j];
            if (iv >= HN) iv = HN - 1;   // safety clamp (never expected)
            if (iv >= 0) cnt++; else iv = -1;
            pk[1+j] = iv;
        }
        pk[7] = 0;
        #pragma unroll
        for (int j = 0; j < 8; j++) nbr_pack[t*8 + j] = pk[j];
        invd[t] = 1.0f / ((float)cnt + 1.0f + 1e-6f);
    }
}

// ---------------------------------------------------------------------------
// ktrans: x[B][C][H] f32 -> xt[B][H][C] bf16, fused global sum/sumsq reduce
// into 256 partial slots (atomic-contention spread).
// grid = 128 b * 64 h-tiles = 8192 blocks of 256
__global__ void ktrans(const float* __restrict__ x,
                       unsigned short* __restrict__ xt,
                       double* __restrict__ dsp){
    __shared__ float tile[32][65];
    __shared__ double red[8];
    int b  = blockIdx.x >> 6;
    int h0 = (blockIdx.x & 63) << 6;
    int t  = threadIdx.x;
    int hh = t & 63;
    int cq = t >> 6;                      // 0..3
    double ds = 0.0, ds2 = 0.0;
    #pragma unroll
    for (int rep = 0; rep < 8; rep++){
        int c = rep*4 + cq;
        float v = x[((size_t)(b*32 + c))*HN + h0 + hh];
        tile[c][hh] = v;
        double dv = (double)v;
        ds += dv; ds2 += dv*dv;
    }
    // wave + block reduce for std
    #pragma unroll
    for (int off = 32; off; off >>= 1){
        ds  += __shfl_down(ds,  off);
        ds2 += __shfl_down(ds2, off);
    }
    int lane = t & 63, wv = t >> 6;
    if (lane == 0){ red[wv] = ds; red[4+wv] = ds2; }
    __syncthreads();
    if (t == 0){
        int slot = blockIdx.x & 255;
        atomicAdd(&dsp[slot*2],     red[0]+red[1]+red[2]+red[3]);
        atomicAdd(&dsp[slot*2 + 1], red[4]+red[5]+red[6]+red[7]);
    }
    // transposed bf16 write: 16B per thread, fully coalesced per wave
    int hw = t >> 2;
    int cg = (t & 3) * 8;
    alignas(16) unsigned short tmp[8];
    #pragma unroll
    for (int j = 0; j < 8; j++) tmp[j] = f32_to_bf16(tile[cg + j][hw]);
    *(uint4*)(xt + ((size_t)(b*HN + h0 + hw))*32 + cg) = *(const uint4*)tmp;
}

// ---------------------------------------------------------------------------
// kwt: reduce std partials; fold 1/(std+1e-5) into weights; pack wt[o][kk][c]
__global__ void kwt(const float* __restrict__ w,
                    const double* __restrict__ dsp,
                    unsigned short* __restrict__ wt){
    __shared__ double sred[8];
    __shared__ float sinv;
    int t = threadIdx.x;                  // 0..255
    double d0 = dsp[t*2], d1 = dsp[t*2 + 1];
    #pragma unroll
    for (int off = 32; off; off >>= 1){
        d0 += __shfl_down(d0, off);
        d1 += __shfl_down(d1, off);
    }
    int lane = t & 63, wv = t >> 6;
    if (lane == 0){ sred[wv] = d0; sred[4+wv] = d1; }
    __syncthreads();
    if (t == 0){
        double sum   = sred[0]+sred[1]+sred[2]+sred[3];
        double sumsq = sred[4]+sred[5]+sred[6]+sred[7];
        double mean = sum / (double)NTOT;
        double var  = (sumsq - (double)NTOT*mean*mean) / (double)(NTOT - 1);
        sinv = 1.0f / ((float)sqrt(var) + 1e-5f);
    }
    __syncthreads();
    float inv_s = sinv;
    for (int i = t; i < COUT*K7*CIN; i += blockDim.x){
        int o  = i / (K7*CIN);
        int kk = (i / CIN) % K7;
        int c  = i % CIN;
        float val = w[(o*CIN + c)*K7 + kk] * inv_s;
        wt[i] = f32_to_bf16(val);
    }
}

// ---------------------------------------------------------------------------
// kconv: gather + MFMA GEMM + /D + bias, write out_pre, accumulate BN stat
// partials into 256 slots. Per wave-tile: 16 h, M=32, K=224 (7 taps).
// grid = 2048 blocks * 256 = 8192 waves; 32768 tiles -> 4 per wave.
__global__ __launch_bounds__(256) void kconv(
    const unsigned short* __restrict__ xt,
    const unsigned short* __restrict__ wt,
    const int* __restrict__ nbrp,
    const float* __restrict__ invd,
    const float* __restrict__ bias,
    float* __restrict__ out,
    float* __restrict__ ostatp)
{
    int lane = threadIdx.x & 63;
    int wv   = threadIdx.x >> 6;
    int wgid = blockIdx.x*4 + wv;         // 0..8191
    int n    = lane & 15;
    int quad = lane >> 4;

    // A fragments (W) in registers: lane holds W[o=n+16mt][ik=kk*32 + quad*8 + j]
    short8 af[2][K7];
    #pragma unroll
    for (int mt = 0; mt < 2; mt++){
        int o = n + 16*mt;
        #pragma unroll
        for (int kk = 0; kk < K7; kk++)
            af[mt][kk] = *(const short8*)(wt + (size_t)(o*K7 + kk)*CIN + quad*8);
    }
    // bias for this lane's 8 output channels (o = mt*16 + quad*4 + r)
    float bias8[2][4];
    #pragma unroll
    for (int mt = 0; mt < 2; mt++)
        #pragma unroll
        for (int r = 0; r < 4; r++)
            bias8[mt][r] = bias[mt*16 + quad*4 + r];

    float sacc[8]  = {0,0,0,0,0,0,0,0};
    float sacc2[8] = {0,0,0,0,0,0,0,0};
    const short8 zero8 = {0,0,0,0,0,0,0,0};

    for (int tilei = wgid; tilei < (NBH/16); tilei += 8192){
        int b  = tilei >> 8;              // 256 tiles per b
        int h0 = (tilei & 255) << 4;
        int h  = h0 + n;
        float idv = invd[h];
        const int* np = nbrp + h*8;

        // preload all 7 gathered B-fragments (independent loads, overlap latency)
        short8 bfr[K7];
        #pragma unroll
        for (int kk = 0; kk < K7; kk++){
            int row  = np[kk];
            int rowc = row < 0 ? 0 : row;
            bfr[kk] = *(const short8*)(xt + ((size_t)(b*HN + rowc))*32 + quad*8);
            if (row < 0) bfr[kk] = zero8;
        }
        f32x4 acc0 = {0.f,0.f,0.f,0.f};
        f32x4 acc1 = {0.f,0.f,0.f,0.f};
        #pragma unroll
        for (int kk = 0; kk < K7; kk++){
            acc0 = __builtin_amdgcn_mfma_f32_16x16x32_bf16(af[0][kk], bfr[kk], acc0, 0, 0, 0);
            acc1 = __builtin_amdgcn_mfma_f32_16x16x32_bf16(af[1][kk], bfr[kk], acc1, 0, 0, 0);
        }
        // epilogue: D[row=quad*4+r][col=n];  out[b][o][h], o = mt*16+quad*4+r
        #pragma unroll
        for (int mt = 0; mt < 2; mt++){
            f32x4 a = mt ? acc1 : acc0;
            #pragma unroll
            for (int r = 0; r < 4; r++){
                int o = mt*16 + quad*4 + r;
                float v = a[r]*idv + bias8[mt][r];
                out[((size_t)(b*COUT + o))*HN + h] = v;
                sacc[mt*4 + r]  += v;
                sacc2[mt*4 + r] += v*v;
            }
        }
    }
    // reduce BN partials over the 16 n-lanes
    #pragma unroll
    for (int bit = 1; bit < 16; bit <<= 1){
        #pragma unroll
        for (int i = 0; i < 8; i++){
            sacc[i]  += __shfl_xor(sacc[i],  bit);
            sacc2[i] += __shfl_xor(sacc2[i], bit);
        }
    }
    if (n == 0){
        int slot = blockIdx.x & 255;
        #pragma unroll
        for (int mt = 0; mt < 2; mt++)
            #pragma unroll
            for (int r = 0; r < 4; r++){
                int o = mt*16 + quad*4 + r;
                atomicAdd(&ostatp[slot*64 + o],      sacc[mt*4 + r]);
                atomicAdd(&ostatp[slot*64 + 32 + o], sacc2[mt*4 + r]);
            }
    }
}

// ---------------------------------------------------------------------------
// kred: fold ostatp[256][64] -> ostat[64]. One block of 256 threads.
__global__ void kred(const float* __restrict__ ostatp,
                     float* __restrict__ ostat){
    __shared__ float part[4][64];
    int t = threadIdx.x;
    int a = t & 63;
    int g = t >> 6;                       // 0..3
    float s = 0.0f;
    #pragma unroll
    for (int j = 0; j < 64; j++)
        s += ostatp[(g*64 + j)*64 + a];
    part[g][a] = s;
    __syncthreads();
    if (t < 64)
        ostat[t] = part[0][t] + part[1][t] + part[2][t] + part[3][t];
}

// ---------------------------------------------------------------------------
// kbn: apply BatchNorm (training-mode, biased var) in place on d_out
__global__ void kbn(float4* __restrict__ out4,
                    const float* __restrict__ ostat,
                    const float* __restrict__ gamma,
                    const float* __restrict__ beta){
    __shared__ float sc[32], sh[32];
    int t = threadIdx.x;
    if (t < 32){
        float mean = ostat[t] * (1.0f/(float)NBH);
        float var  = ostat[32 + t] * (1.0f/(float)NBH) - mean*mean;
        float s = gamma[t] * rsqrtf(var + 1e-5f);
        sc[t] = s;
        sh[t] = beta[t] - mean*s;
    }
    __syncthreads();
    int gid    = blockIdx.x*blockDim.x + t;
    int stride = gridDim.x*blockDim.x;
    for (int i = gid; i < NTOT/4; i += stride){
        int o = (i >> 10) & 31;           // (i*4 / 4096) % 32
        float4 v = out4[i];
        float s = sc[o], b = sh[o];
        v.x = v.x*s + b; v.y = v.y*s + b; v.z = v.z*s + b; v.w = v.w*s + b;
        out4[i] = v;
    }
}

// ---------------------------------------------------------------------------
extern "C" void kernel_launch(void* const* d_in, const int* in_sizes, int n_in,
                              void* d_out, int out_size, void* d_ws, size_t ws_size,
                              hipStream_t stream) {
    const float* x      = (const float*)d_in[0];
    const float* weight = (const float*)d_in[1];
    const float* bias   = (const float*)d_in[2];
    const float* gamma  = (const float*)d_in[3];
    const float* beta   = (const float*)d_in[4];
    const int*   nbr    = (const int*)d_in[5];   // int64 in reference -> int32 from harness
    // d_in[6] = groups (==1), ignored

    char* ws = (char*)d_ws;
    unsigned short* xt    = (unsigned short*)(ws + WS_XT);
    unsigned short* wt    = (unsigned short*)(ws + WS_WT);
    int*            nbrp  = (int*)(ws + WS_NBR);
    float*          invd  = (float*)(ws + WS_INVD);
    double*         dsp   = (double*)(ws + WS_DSP);
    float*          ostat = (float*)(ws + WS_OST);
    float*          ostatp= (float*)(ws + WS_OSTP);
    float*          out   = (float*)d_out;

    kprep <<<16,   256, 0, stream>>>(nbr, nbrp, invd, dsp, ostatp);
    ktrans<<<8192, 256, 0, stream>>>(x, xt, dsp);
    kwt   <<<1,    256, 0, stream>>>(weight, dsp, wt);
    kconv <<<2048, 256, 0, stream>>>(xt, wt, nbrp, invd, bias, out, ostatp);
    kred  <<<1,    256, 0, stream>>>(ostatp, ostat);
    kbn   <<<2048, 256, 0, stream>>>((float4*)out, ostat, gamma, beta);
}

// Round 4
// 184.915 us; speedup vs baseline: 5.7351x; 1.1036x over previous
//
#include <hip/hip_runtime.h>
#include <stdint.h>
#include <stddef.h>

// Problem constants
#define BSZ 128
#define CIN 32
#define COUT 32
#define HN 4096
#define K7 7
#define NTOT (BSZ*CIN*HN)     // 16,777,216 elements
#define NBH  (BSZ*HN)         // 524,288 (b,h) pairs

typedef __attribute__((ext_vector_type(8))) short short8;
typedef __attribute__((ext_vector_type(4))) float f32x4;

// ws layout (bytes). NOTE: xt lives in the UPPER HALF OF d_out (d_out is 67MB
// f32; xt is 33.5MB bf16, dead before kbn overwrites d_out).
#define WS_OB   0            // bf16 out_pre[B][COUT][H]     : 33,554,432 B
#define WS_WT   33554432     // bf16 wt[o][kk][c]            : 14,336 B
#define WS_NBR  33568768     // int32 nbr_pack[H][8]         : 131,072 B
#define WS_INVD 33699840     // float invd[H]                : 16,384 B
#define WS_OSTP 33716224     // float ostatp[256][64]        : 65,536 B
#define WS_OST  33781760     // float ostat[64]              : 256 B

__device__ __forceinline__ unsigned short f32_to_bf16(float f){
    union { float f; uint32_t u; } v; v.f = f;
    uint32_t u = v.u;
    return (unsigned short)((u + 0x7FFFu + ((u >> 16) & 1u)) >> 16);
}
__device__ __forceinline__ float bf16_to_f32(unsigned short h){
    union { uint32_t u; float f; } v; v.u = ((uint32_t)h) << 16;
    return v.f;
}

// ---------------------------------------------------------------------------
// kinit: blocks 0..15 build neighbor table + invd + zero ostatp;
//        block 16 packs weights (bf16, A-fragment order; NO std folding —
//        BatchNorm exactly cancels the global scale and the bias).
// NOTE: harness passes integer inputs as int32 (not the reference's int64).
__global__ void kinit(const int* __restrict__ nbr,
                      const float* __restrict__ w,
                      int* __restrict__ nbr_pack,
                      float* __restrict__ invd,
                      unsigned short* __restrict__ wt,
                      float* __restrict__ ostatp){
    int t = threadIdx.x;
    if (blockIdx.x < 16){
        int h = blockIdx.x*256 + t;       // 0..4095
        #pragma unroll
        for (int j = 0; j < 4; j++) ostatp[h*4 + j] = 0.0f;   // 16384 floats
        int cnt = 0;
        int pk[8];
        #pragma unroll
        for (int j = 0; j < 6; j++){
            int iv = nbr[h*6 + j];
            if (iv >= HN) iv = HN - 1;    // safety clamp (never expected)
            if (iv >= 0) cnt++; else iv = -1;
            pk[j] = iv;
        }
        pk[6] = cnt; pk[7] = 0;
        #pragma unroll
        for (int j = 0; j < 8; j++) nbr_pack[h*8 + j] = pk[j];
        invd[h] = 1.0f / ((float)cnt + 1.0f + 1e-6f);
    } else {
        for (int i = t; i < COUT*K7*CIN; i += 256){
            int o  = i / (K7*CIN);
            int kk = (i / CIN) % K7;
            int c  = i % CIN;
            wt[i] = f32_to_bf16(w[(o*CIN + c)*K7 + kk]);
        }
    }
}

// ---------------------------------------------------------------------------
// ktrans: pure transpose x[B][C][H] f32 -> xt[B][H][C] bf16 (no stats).
// grid = 128 b * 16 h-tiles(256h) = 2048 blocks of 256.
__global__ void ktrans(const float* __restrict__ x,
                       unsigned short* __restrict__ xt){
    __shared__ float tile[32][260];       // rows 16B-aligned (260*4=1040)
    int b  = blockIdx.x >> 4;
    int h0 = (blockIdx.x & 15) << 8;
    int t  = threadIdx.x;
    #pragma unroll
    for (int l = 0; l < 8; l++){
        int linear = l*256 + t;
        int c  = linear >> 6;
        int h4 = linear & 63;
        float4 v = *(const float4*)(x + ((size_t)(b*CIN + c))*HN + h0 + h4*4);
        *(float4*)&tile[c][h4*4] = v;     // contiguous b128 stores: conflict-free
    }
    __syncthreads();
    int cg = (t & 3) * 8;
    int hw = t >> 2;                      // 0..63
    #pragma unroll
    for (int r = 0; r < 4; r++){
        int h = r*64 + hw;
        alignas(16) unsigned short tmp[8];
        #pragma unroll
        for (int j = 0; j < 8; j++) tmp[j] = f32_to_bf16(tile[cg + j][h]);
        *(uint4*)(xt + ((size_t)(b*HN + h0 + h))*32 + cg) = *(const uint4*)tmp;
    }
}

// ---------------------------------------------------------------------------
// kconv: gather + MFMA + /D, write bf16 out_pre, accumulate BN stat partials.
// XCD-locality swizzle: blk&7 = XCD slot; each XCD works on 16 b's only, so
// its 4MB L2 holds exactly those xt slices (16 x 256KB) -> gathers are L2 hits.
// 2048 blocks; block owns one b and 256 consecutive h (4 waves x 4 tiles x 16h).
__global__ __launch_bounds__(256) void kconv(
    const unsigned short* __restrict__ xt,
    const unsigned short* __restrict__ wt,
    const int* __restrict__ nbrp,
    const float* __restrict__ invd,
    unsigned short* __restrict__ ob,
    float* __restrict__ ostatp)
{
    int lane = threadIdx.x & 63;
    int wv   = threadIdx.x >> 6;
    int n    = lane & 15;
    int quad = lane >> 4;
    int xcd  = blockIdx.x & 7;
    int j    = blockIdx.x >> 3;           // 0..255
    int b    = xcd*16 + (j >> 4);
    int hbase= ((j & 15)*4 + wv) * 64;    // this wave: h in [hbase, hbase+64)

    // A fragments (W): lane holds W[o=n+16mt][ik=kk*32 + quad*8 + jj]
    short8 af[2][K7];
    #pragma unroll
    for (int mt = 0; mt < 2; mt++){
        int o = n + 16*mt;
        #pragma unroll
        for (int kk = 0; kk < K7; kk++)
            af[mt][kk] = *(const short8*)(wt + (size_t)(o*K7 + kk)*CIN + quad*8);
    }

    float sacc[8]  = {0,0,0,0,0,0,0,0};
    float sacc2[8] = {0,0,0,0,0,0,0,0};
    const short8 zero8 = {0,0,0,0,0,0,0,0};
    const unsigned short* xb = xt + (size_t)b*HN*CIN;

    // prefetch tile 0's neighbor rows + invd
    int h = hbase + n;
    int4 na = *(const int4*)(nbrp + h*8);
    int4 nb = *(const int4*)(nbrp + h*8 + 4);
    float idv = invd[h];

    #pragma unroll 1
    for (int it = 0; it < 4; it++){
        int hc = hbase + it*16 + n;
        // prefetch next tile's table entries (dummy-reload current on last)
        int hn = hbase + (it < 3 ? it+1 : it)*16 + n;
        int4 na2 = *(const int4*)(nbrp + hn*8);
        int4 nb2 = *(const int4*)(nbrp + hn*8 + 4);
        float idv2 = invd[hn];

        short8 bfr[K7];
        bfr[0] = *(const short8*)(xb + (size_t)hc*CIN + quad*8);   // self tap
        int rows[6] = {na.x, na.y, na.z, na.w, nb.x, nb.y};
        #pragma unroll
        for (int kk = 0; kk < 6; kk++){
            int row  = rows[kk];
            int rowc = row < 0 ? 0 : row;
            bfr[kk+1] = *(const short8*)(xb + (size_t)rowc*CIN + quad*8);
            if (row < 0) bfr[kk+1] = zero8;
        }
        f32x4 acc0 = {0.f,0.f,0.f,0.f};
        f32x4 acc1 = {0.f,0.f,0.f,0.f};
        #pragma unroll
        for (int kk = 0; kk < K7; kk++){
            acc0 = __builtin_amdgcn_mfma_f32_16x16x32_bf16(af[0][kk], bfr[kk], acc0, 0, 0, 0);
            acc1 = __builtin_amdgcn_mfma_f32_16x16x32_bf16(af[1][kk], bfr[kk], acc1, 0, 0, 0);
        }
        // epilogue: D[row=quad*4+r][col=n]; o = mt*16+quad*4+r
        #pragma unroll
        for (int mt = 0; mt < 2; mt++){
            f32x4 a = mt ? acc1 : acc0;
            #pragma unroll
            for (int r = 0; r < 4; r++){
                int o = mt*16 + quad*4 + r;
                float v = a[r]*idv;
                ob[((size_t)(b*COUT + o))*HN + hc] = f32_to_bf16(v);
                sacc[mt*4 + r]  += v;
                sacc2[mt*4 + r] += v*v;
            }
        }
        na = na2; nb = nb2; idv = idv2;
    }
    // reduce BN partials over the 16 n-lanes
    #pragma unroll
    for (int bit = 1; bit < 16; bit <<= 1){
        #pragma unroll
        for (int i = 0; i < 8; i++){
            sacc[i]  += __shfl_xor(sacc[i],  bit);
            sacc2[i] += __shfl_xor(sacc2[i], bit);
        }
    }
    if (n == 0){
        int slot = blockIdx.x & 255;
        #pragma unroll
        for (int mt = 0; mt < 2; mt++)
            #pragma unroll
            for (int r = 0; r < 4; r++){
                int o = mt*16 + quad*4 + r;
                atomicAdd(&ostatp[slot*64 + o],      sacc[mt*4 + r]);
                atomicAdd(&ostatp[slot*64 + 32 + o], sacc2[mt*4 + r]);
            }
    }
}

// ---------------------------------------------------------------------------
// kred: fold ostatp[256][64] -> ostat[64]. One block of 256 threads.
__global__ void kred(const float* __restrict__ ostatp,
                     float* __restrict__ ostat){
    __shared__ float part[4][64];
    int t = threadIdx.x;
    int a = t & 63;
    int g = t >> 6;
    float s = 0.0f;
    #pragma unroll
    for (int j = 0; j < 64; j++)
        s += ostatp[(g*64 + j)*64 + a];
    part[g][a] = s;
    __syncthreads();
    if (t < 64)
        ostat[t] = part[0][t] + part[1][t] + part[2][t] + part[3][t];
}

// ---------------------------------------------------------------------------
// kbn: read bf16 out_pre, apply BatchNorm (biased var), write f32 d_out.
__global__ void kbn(const unsigned short* __restrict__ ob,
                    float* __restrict__ out,
                    const float* __restrict__ ostat,
                    const float* __restrict__ gamma,
                    const float* __restrict__ beta){
    __shared__ float sc[32], sh[32];
    int t = threadIdx.x;
    if (t < 32){
        float mean = ostat[t] * (1.0f/(float)NBH);
        float var  = ostat[32 + t] * (1.0f/(float)NBH) - mean*mean;
        float s = gamma[t] * rsqrtf(var + 1e-5f);
        sc[t] = s;
        sh[t] = beta[t] - mean*s;
    }
    __syncthreads();
    int gid    = blockIdx.x*blockDim.x + t;
    int stride = gridDim.x*blockDim.x;
    for (int i = gid; i < NTOT/8; i += stride){
        int o = (i >> 9) & 31;            // (i*8 / 4096) % 32
        uint4 raw = ((const uint4*)ob)[i];
        const unsigned short* p = (const unsigned short*)&raw;
        float s = sc[o], bsh = sh[o];
        float4 r0, r1;
        r0.x = bf16_to_f32(p[0])*s + bsh;
        r0.y = bf16_to_f32(p[1])*s + bsh;
        r0.z = bf16_to_f32(p[2])*s + bsh;
        r0.w = bf16_to_f32(p[3])*s + bsh;
        r1.x = bf16_to_f32(p[4])*s + bsh;
        r1.y = bf16_to_f32(p[5])*s + bsh;
        r1.z = bf16_to_f32(p[6])*s + bsh;
        r1.w = bf16_to_f32(p[7])*s + bsh;
        ((float4*)out)[i*2]     = r0;
        ((float4*)out)[i*2 + 1] = r1;
    }
}

// ---------------------------------------------------------------------------
extern "C" void kernel_launch(void* const* d_in, const int* in_sizes, int n_in,
                              void* d_out, int out_size, void* d_ws, size_t ws_size,
                              hipStream_t stream) {
    const float* x      = (const float*)d_in[0];
    const float* weight = (const float*)d_in[1];
    // d_in[2] = bias  — exactly cancelled by BatchNorm mean subtraction
    const float* gamma  = (const float*)d_in[3];
    const float* beta   = (const float*)d_in[4];
    const int*   nbr    = (const int*)d_in[5];   // int64 in reference -> int32 from harness
    // d_in[6] = groups (==1), ignored

    char* ws = (char*)d_ws;
    unsigned short* ob    = (unsigned short*)(ws + WS_OB);
    unsigned short* wt    = (unsigned short*)(ws + WS_WT);
    int*            nbrp  = (int*)(ws + WS_NBR);
    float*          invd  = (float*)(ws + WS_INVD);
    float*          ostatp= (float*)(ws + WS_OSTP);
    float*          ostat = (float*)(ws + WS_OST);
    float*          out   = (float*)d_out;
    // xt (bf16, 33.5MB) lives in the upper half of d_out; dead before kbn
    // overwrites d_out (stream-ordered).
    unsigned short* xt    = (unsigned short*)d_out + 16777216;

    kinit <<<17,   256, 0, stream>>>(nbr, weight, nbrp, invd, wt, ostatp);
    ktrans<<<2048, 256, 0, stream>>>(x, xt);
    kconv <<<2048, 256, 0, stream>>>(xt, wt, nbrp, invd, ob, ostatp);
    kred  <<<1,    256, 0, stream>>>(ostatp, ostat);
    kbn   <<<2048, 256, 0, stream>>>(ob, out, ostat, gamma, beta);
}